// Round 10
// baseline (363.360 us; speedup 1.0000x reference)
//
#include <hip/hip_runtime.h>
#include <hip/hip_bf16.h>

#define EPS 1e-5f
#define MM 256     // MSA depth m
#define NN 384     // sequence length i/j
#define DM 256     // dim_msa
#define DH 32      // hidden dh
#define DP 128     // dim_pairwise
#define NIC (NN*DH)  // 12288

typedef __attribute__((ext_vector_type(8))) _Float16 half8;
typedef __attribute__((ext_vector_type(4))) float floatx4;

__device__ __forceinline__ void load16_to_lds(const void* gptr, void* lptr) {
    __builtin_amdgcn_global_load_lds(
        (const __attribute__((address_space(1))) void*)gptr,
        (__attribute__((address_space(3))) void*)lptr,
        16, 0, 0);
}

// float -> fp16 bits (RTNE). fp16 (10 mantissa bits) vs bf16 (7) cuts every
// quantization stage's error 8x; all intermediates are range-safe for fp16
// (|xn|<~6, |L/R|<~2, |G|<~15, weights ~0.02). MFMA f16 rate == bf16 rate.
__device__ __forceinline__ unsigned short f2h_bits(float f) {
    _Float16 h = (_Float16)f;
    union { _Float16 h; unsigned short u; } cvt;
    cvt.h = h;
    return cvt.u;
}

// ---------------------------------------------------------------------------
// KPREP: merged preprocessing (one launch, 92 blocks x 256):
//   bid 0..15  : k0a — wo [1024 cd][128 p] f32 -> woT2 [128 p][1024] fp16,
//                slice-major woT2[p][s*256 + d*8 + (c&7)], s = c>>3.
//   bid 16..79 : k0b — WbT[64 c][256 k] fp16 + bias[64].
//   bid 80..91 : k2a — bitpack mask: pack[i*8+tw] = bits of mask[tw*32..+31][i]
// ---------------------------------------------------------------------------
__global__ __launch_bounds__(256) void kprep(
    const float* __restrict__ wo, unsigned short* __restrict__ woT2,
    const float* __restrict__ wl, const float* __restrict__ bl,
    const float* __restrict__ wr, const float* __restrict__ br,
    unsigned short* __restrict__ WbT, float* __restrict__ bias,
    const int* __restrict__ mask, unsigned int* __restrict__ pack)
{
    __shared__ float ts[64*129];
    const int bid = blockIdx.x;
    const int t   = threadIdx.x;

    if (bid < 16) {
        // ---- k0a: woT2 packing ----
        const int s  = bid >> 2;
        const int dg = bid & 3;
        #pragma unroll
        for (int g = 0; g < 32; g++) {
            int idx = g*256 + t;
            int row = idx >> 7, p = idx & 127;   // row = ci*8 + di
            int ci = row >> 3, di = row & 7;
            int cd = (s*8 + ci)*32 + dg*8 + di;
            ts[row*129 + p] = wo[(size_t)cd*DP + p];
        }
        __syncthreads();
        int p = t >> 1, half = t & 1;
        #pragma unroll
        for (int dq = 0; dq < 4; dq++) {
            int di = half*4 + dq;
            #pragma unroll
            for (int cq = 0; cq < 2; cq++) {
                ushort4 u;
                u.x = f2h_bits(ts[((cq*4+0)*8 + di)*129 + p]);
                u.y = f2h_bits(ts[((cq*4+1)*8 + di)*129 + p]);
                u.z = f2h_bits(ts[((cq*4+2)*8 + di)*129 + p]);
                u.w = f2h_bits(ts[((cq*4+3)*8 + di)*129 + p]);
                *(ushort4*)&woT2[(size_t)p*1024 + s*256 + dg*64 + di*8 + cq*4] = u;
            }
        }
    } else if (bid < 80) {
        // ---- k0b: WbT + bias ----
        const int c = bid - 16, k = t;
        float v = (c < DH) ? wl[k*DH + c] : wr[k*DH + (c - DH)];
        WbT[c*256 + k] = f2h_bits(v);
        if (c == 0 && k < 64) bias[k] = (k < DH) ? bl[k] : br[k - DH];
    } else {
        // ---- k2a: mask bitpack, coalesced over i ----
        int id = (bid - 80)*256 + t;          // 0..3071
        int i = id % NN, tw = id / NN;        // tw in [0,8)
        unsigned int wbits = 0;
        #pragma unroll
        for (int b = 0; b < 32; b++)
            wbits |= (mask[(tw*32 + b)*NN + i] != 0 ? 1u : 0u) << b;
        pack[i*8 + tw] = wbits;
    }
}

// ---------------------------------------------------------------------------
// K2: cinv[i,j] = 1/(popcount-AND over m + EPS)
// ---------------------------------------------------------------------------
__global__ __launch_bounds__(256) void k2_count(
    const unsigned int* __restrict__ pack, float* __restrict__ cinv)
{
    int id = blockIdx.x * 256 + threadIdx.x;
    int i = id / NN, j = id % NN;
    int s = 0;
    #pragma unroll
    for (int tw = 0; tw < 8; tw++)
        s += __popc(pack[i*8 + tw] & pack[j*8 + tw]);
    cinv[id] = 1.0f / ((float)s + EPS);
}

// ---------------------------------------------------------------------------
// K1: LN (f32) + MFMA projection -> Lb/Rb in [ic][m] layout (fp16).
// Structure frozen from r8; only dtype changed (bf16->fp16).
// ---------------------------------------------------------------------------
__global__ __launch_bounds__(256, 2) void k1_lnproj(
    const float* __restrict__ x, const int* __restrict__ mask,
    const float* __restrict__ ln_g, const float* __restrict__ ln_b,
    const unsigned short* __restrict__ WbTg, const float* __restrict__ bias,
    unsigned short* __restrict__ Lb, unsigned short* __restrict__ Rb)
{
    __shared__ unsigned short xns[64*264];   // [mlocal][k] padded (+8)
    __shared__ float mfs[64];

    const int i  = blockIdx.x;
    const int mc = blockIdx.y;               // m-chunk (64 rows)
    const int t = threadIdx.x;
    const int l = t & 63, w = t >> 6;
    const int lc = l & 15, quad = l >> 4;
    const int sub = l >> 4, lc4 = l & 15;    // 16-lane group id / lane-in-group

    // gamma/beta for k = g*64 + lc4*4 .. +3
    float4 gk[4], bk[4];
    #pragma unroll
    for (int g = 0; g < 4; g++) {
        gk[g] = *(const float4*)&ln_g[g*64 + lc4*4];
        bk[g] = *(const float4*)&ln_b[g*64 + lc4*4];
    }

    // batch-issue all 16 loads (4 rows x 4 segments per wave)
    float4 v[4][4];
    #pragma unroll
    for (int rr = 0; rr < 4; rr++) {
        int mlocal = w*16 + rr*4 + sub;
        int m = mc*64 + mlocal;
        const float4* xr = (const float4*)&x[((size_t)m*NN + i)*DM];
        #pragma unroll
        for (int g = 0; g < 4; g++)
            v[rr][g] = xr[g*16 + lc4];       // 256B contiguous per instr
    }

    #pragma unroll
    for (int rr = 0; rr < 4; rr++) {
        int mlocal = w*16 + rr*4 + sub;
        int m = mc*64 + mlocal;
        float s = 0.f, s2 = 0.f;
        #pragma unroll
        for (int g = 0; g < 4; g++) {
            float4 vg = v[rr][g];
            s  += vg.x + vg.y + vg.z + vg.w;
            s2 += vg.x*vg.x + vg.y*vg.y + vg.z*vg.z + vg.w*vg.w;
        }
        #pragma unroll
        for (int off = 1; off < 16; off <<= 1) {
            s  += __shfl_xor(s,  off, 64);
            s2 += __shfl_xor(s2, off, 64);
        }
        float mu   = s * (1.0f/DM);
        float var  = s2 * (1.0f/DM) - mu*mu;
        float rstd = rsqrtf(var + EPS);
        #pragma unroll
        for (int g = 0; g < 4; g++) {
            float4 vg = v[rr][g];
            ushort4 u;
            u.x = f2h_bits((vg.x - mu)*rstd*gk[g].x + bk[g].x);
            u.y = f2h_bits((vg.y - mu)*rstd*gk[g].y + bk[g].y);
            u.z = f2h_bits((vg.z - mu)*rstd*gk[g].z + bk[g].z);
            u.w = f2h_bits((vg.w - mu)*rstd*gk[g].w + bk[g].w);
            *(ushort4*)&xns[mlocal*264 + g*64 + lc4*4] = u;
        }
        if (lc4 == 0) mfs[mlocal] = (mask[(size_t)m*NN + i] != 0) ? 1.0f : 0.0f;
    }
    __syncthreads();

    // MFMA: D[m][c] = sum_k xn[m][k] * WbT[c][k]   (fp16 MFMA)
    floatx4 acc[4];
    #pragma unroll
    for (int nt = 0; nt < 4; nt++) acc[nt] = (floatx4){0.f,0.f,0.f,0.f};
    #pragma unroll
    for (int ks = 0; ks < 8; ks++) {
        half8 af = *(const half8*)&xns[(w*16 + lc)*264 + ks*32 + quad*8];
        #pragma unroll
        for (int nt = 0; nt < 4; nt++) {
            half8 bf = *(const half8*)&WbTg[(nt*16 + lc)*256 + ks*32 + quad*8];
            acc[nt] = __builtin_amdgcn_mfma_f32_16x16x32_f16(af, bf, acc[nt], 0, 0, 0);
        }
    }
    __syncthreads();   // done reading xns; reuse as transpose buffer

    // bias + mask, write transposed tile tr[c][mlocal]
    unsigned short* tr = xns;   // [64][72]
    #pragma unroll
    for (int nt = 0; nt < 4; nt++) {
        int c = nt*16 + lc;
        float bv = bias[c];
        #pragma unroll
        for (int rg = 0; rg < 4; rg++) {
            int mlocal = w*16 + quad*4 + rg;
            tr[c*72 + mlocal] = f2h_bits((acc[nt][rg] + bv) * mfs[mlocal]);
        }
    }
    __syncthreads();

    // write out: thread t -> c = t>>2, m-segment (t&3)*16 (contig in m)
    {
        int c = t >> 2, seg = t & 3;
        unsigned short* dst = (c < DH)
            ? &Lb[((size_t)(i*DH + c))*MM + mc*64 + seg*16]
            : &Rb[((size_t)(i*DH + (c - DH)))*MM + mc*64 + seg*16];
        #pragma unroll
        for (int q = 0; q < 4; q++)
            *(ushort4*)&dst[q*4] = *(ushort4*)&tr[c*72 + seg*16 + q*4];
    }
}

// ---------------------------------------------------------------------------
// K3f: fused GEMM1 + projection, 256x256 tile, 8 waves (512 thr), fp16.
// Body structure IDENTICAL to the r8-verified BK=32 schedule; dtype fp16,
// and bid = blockIdx.x + bofs so the 2304-block grid is issued as FOUR
// dispatches (512+512+512+768 = 2+2+2+3 CU-epochs, zero tail waste) so
// sub-175us dispatches (k1 etc.) surface in the profile top-5.
// ---------------------------------------------------------------------------
__global__ __launch_bounds__(512, 2) void k3f_gemm(
    const unsigned short* __restrict__ Lb,   // [NIC][MM] fp16
    const unsigned short* __restrict__ Rb,   // [NIC][MM] fp16
    const unsigned short* __restrict__ woT2, // [128 p][1024] slice-major fp16
    const float* __restrict__ bo, const float* __restrict__ cinv,
    float* __restrict__ out, int bofs)
{
    __shared__ short smem[32768];            // 64 KB: 2 x (A 16K | B 16K); union gp[64][264]
    const int t = threadIdx.x;
    const int l = t & 63, w = t >> 6;
    const int wx = w & 3, wy = w >> 2;
    const int lc = l & 15, quad = l >> 4;

    // XCD-aware bijective swizzle, A-panel-resident walk (2304 = 8*48*6)
    int bid = blockIdx.x + bofs;
    int xcd = bid & 7;
    int local = bid >> 3;        // 0..287
    int bx = local / 6;          // 0..47, slow-varying within XCD
    int by = xcd * 6 + (local % 6);

    const size_t arow0 = (size_t)bx * 256;
    const size_t brow0 = (size_t)by * 256;

    // staging decode: thread t owns 16B chunks pos0 = t, pos1 = 512+t
    const int pos0 = t, pos1 = 512 + t;
    const int line0 = pos0 >> 3, c0 = (pos0 & 7) ^ (line0 & 7);
    const int r0 = line0*2 + (c0 >> 2), k00 = (c0 & 3) * 8;
    const int line1 = pos1 >> 3, c1 = (pos1 & 7) ^ (line1 & 7);
    const int r1 = line1*2 + (c1 >> 2), k01 = (c1 & 3) * 8;

    const unsigned short* srcA0 = Lb + (arow0 + r0)*MM + k00;
    const unsigned short* srcA1 = Lb + (arow0 + r1)*MM + k01;
    const unsigned short* srcB0 = Rb + (brow0 + r0)*MM + k00;
    const unsigned short* srcB1 = Rb + (brow0 + r1)*MM + k01;

    floatx4 acc[8][4];
    #pragma unroll
    for (int a = 0; a < 8; a++)
        #pragma unroll
        for (int b = 0; b < 4; b++) acc[a][b] = (floatx4){0.f,0.f,0.f,0.f};

#define STAGE(bsel, step) do {                                           \
        char* sb = (char*)smem + (bsel)*32768;                           \
        load16_to_lds(srcA0 + (step)*32, sb + pos0*16);                  \
        load16_to_lds(srcA1 + (step)*32, sb + pos1*16);                  \
        load16_to_lds(srcB0 + (step)*32, sb + 16384 + pos0*16);          \
        load16_to_lds(srcB1 + (step)*32, sb + 16384 + pos1*16);          \
    } while (0)

    STAGE(0, 0);
    STAGE(1, 1);
    #pragma unroll
    for (int tstep = 0; tstep < 8; tstep++) {
        if (tstep < 7) asm volatile("s_waitcnt vmcnt(4)" ::: "memory");
        else           asm volatile("s_waitcnt vmcnt(0)" ::: "memory");
        __builtin_amdgcn_s_barrier();
        __builtin_amdgcn_sched_barrier(0);   // pin: no reads above barrier
        const char* Ab = (const char*)smem + (tstep & 1)*32768;
        const char* Bb = Ab + 16384;
        half8 bfr[4];
        #pragma unroll
        for (int nt = 0; nt < 4; nt++) {
            int r = wx*64 + nt*16 + lc;
            int li = r >> 1, cc = ((r & 1)*4 + quad) ^ (li & 7);
            bfr[nt] = *(const half8*)(Bb + li*128 + cc*16);
        }
        __builtin_amdgcn_s_setprio(1);
        #pragma unroll
        for (int mt = 0; mt < 8; mt++) {
            int r = wy*128 + mt*16 + lc;
            int li = r >> 1, cc = ((r & 1)*4 + quad) ^ (li & 7);
            half8 af = *(const half8*)(Ab + li*128 + cc*16);
            #pragma unroll
            for (int nt = 0; nt < 4; nt++)
                acc[mt][nt] = __builtin_amdgcn_mfma_f32_16x16x32_f16(
                    af, bfr[nt], acc[mt][nt], 0, 0, 0);
        }
        __builtin_amdgcn_s_setprio(0);
        __builtin_amdgcn_s_barrier();
        __builtin_amdgcn_sched_barrier(0);   // pin: no STAGE above barrier
        if (tstep + 2 < 8) STAGE(tstep & 1, tstep + 2);
    }
#undef STAGE

    // --- epilogue: 4 K-slice rounds, gp union in smem ---
    short* gp = smem;                        // [64 pairs][264]
    const int prow = w*16 + lc;              // p column owned by this lane
    floatx4 acc2[4];
    #pragma unroll
    for (int a = 0; a < 4; a++) acc2[a] = (floatx4){0.f,0.f,0.f,0.f};

    #pragma unroll
    for (int s = 0; s < 4; s++) {
        // prefetch this round's woT2 rows (latency hidden under the scatter)
        half8 b2r[8];
        #pragma unroll
        for (int ks = 0; ks < 8; ks++)
            b2r[ks] = *(const half8*)&woT2[(size_t)prow*1024 + s*256 + ks*32 + quad*8];

        // scatter slice s: elements with c>>3 == s.  c = (mt&1)*16+quad*4+rg
        // -> needs quad>>1 == (s&1) and mt&1 == (s>>1).  kk = d*8 + (c&7).
        if ((quad >> 1) == (s & 1)) {
            #pragma unroll
            for (int mmi = 0; mmi < 4; mmi++) {
                const int mt = (s >> 1) + mmi*2;
                #pragma unroll
                for (int nt = 0; nt < 4; nt++) {
                    int pair = (wy*4 + (mt >> 1))*8 + (wx*2 + (nt >> 1));
                    int d = (nt & 1)*16 + lc;
                    int kk = d*8 + (quad & 1)*4;
                    ushort4 u;
                    u.x = f2h_bits(acc[mt][nt][0]);
                    u.y = f2h_bits(acc[mt][nt][1]);
                    u.z = f2h_bits(acc[mt][nt][2]);
                    u.w = f2h_bits(acc[mt][nt][3]);
                    *(ushort4*)&gp[pair*264 + kk] = u;
                }
            }
        }
        __syncthreads();

        // GEMM2 partial: all 64 pairs x 16 p (this wave) x K-slice 256
        __builtin_amdgcn_s_setprio(1);
        #pragma unroll
        for (int ks = 0; ks < 8; ks++) {
            #pragma unroll
            for (int mt2 = 0; mt2 < 4; mt2++) {
                half8 a2 = *(const half8*)&gp[(mt2*16 + lc)*264 + ks*32 + quad*8];
                acc2[mt2] = __builtin_amdgcn_mfma_f32_16x16x32_f16(
                    a2, b2r[ks], acc2[mt2], 0, 0, 0);
            }
        }
        __builtin_amdgcn_s_setprio(0);
        __syncthreads();
    }

    const float bv = bo[prow];
    #pragma unroll
    for (int mt2 = 0; mt2 < 4; mt2++) {
        #pragma unroll
        for (int rg = 0; rg < 4; rg++) {
            int pair = mt2*16 + quad*4 + rg;
            int i = bx*8 + (pair >> 3);
            int j = by*8 + (pair & 7);
            out[((size_t)(i*NN + j))*DP + prow] =
                (acc2[mt2][rg] + bv) * cinv[i*NN + j];
        }
    }
}

// ---------------------------------------------------------------------------
extern "C" void kernel_launch(void* const* d_in, const int* in_sizes, int n_in,
                              void* d_out, int out_size, void* d_ws, size_t ws_size,
                              hipStream_t stream)
{
    const float* x    = (const float*)d_in[0];
    const int*   mask = (const int*)d_in[1];
    const float* ln_g = (const float*)d_in[2];
    const float* ln_b = (const float*)d_in[3];
    const float* wl   = (const float*)d_in[4];
    const float* bl   = (const float*)d_in[5];
    const float* wr   = (const float*)d_in[6];
    const float* br   = (const float*)d_in[7];
    const float* wo   = (const float*)d_in[8];
    const float* bo   = (const float*)d_in[9];
    float* out = (float*)d_out;

    char* ws = (char*)d_ws;
    size_t off = 0;
    unsigned short* Lb   = (unsigned short*)(ws + off); off += (size_t)NIC*MM*2;  // 6.29 MB
    unsigned short* Rb   = (unsigned short*)(ws + off); off += (size_t)NIC*MM*2;  // 6.29 MB
    unsigned short* woT2 = (unsigned short*)(ws + off); off += (size_t)DP*1024*2; // 0.26 MB
    unsigned short* WbTg = (unsigned short*)(ws + off); off += (size_t)64*256*2;  // 32 KB
    float*          bias = (float*)(ws + off);          off += 64*4;
    float*          cinv = (float*)(ws + off);          off += (size_t)NN*NN*4;   // 0.59 MB
    // pack aliases Lb (12 KB, transient): written by kprep, read by k2_count,
    // both complete (stream order) before k1 writes Lb. Keeps the workspace
    // footprint at the proven 13.46 MB maximum.
    unsigned int*   pack = (unsigned int*)Lb;

    kprep<<<92, 256, 0, stream>>>(wo, woT2, wl, bl, wr, br, WbTg, bias, mask, pack);
    k2_count<<<(NN*NN)/256, 256, 0, stream>>>(pack, cinv);
    k1_lnproj<<<dim3(NN, MM/64), 256, 0, stream>>>(x, mask, ln_g, ln_b, WbTg, bias, Lb, Rb);
    // k3f split: 512+512+512+768 blocks = 2+2+2+3 CU-epochs (9 total, no
    // tail waste) so that sub-175us dispatches surface in the profile.
    k3f_gemm<<< 512, 512, 0, stream>>>(Lb, Rb, woT2, bo, cinv, out, 0);
    k3f_gemm<<< 512, 512, 0, stream>>>(Lb, Rb, woT2, bo, cinv, out, 512);
    k3f_gemm<<< 512, 512, 0, stream>>>(Lb, Rb, woT2, bo, cinv, out, 1024);
    k3f_gemm<<< 768, 512, 0, stream>>>(Lb, Rb, woT2, bo, cinv, out, 1536);
}

// Round 11
// 339.449 us; speedup vs baseline: 1.0704x; 1.0704x over previous
//
#include <hip/hip_runtime.h>
#include <hip/hip_bf16.h>

#define EPS 1e-5f
#define MM 256     // MSA depth m
#define NN 384     // sequence length i/j
#define DM 256     // dim_msa
#define DH 32      // hidden dh
#define DP 128     // dim_pairwise
#define NIC (NN*DH)  // 12288

typedef __attribute__((ext_vector_type(8))) _Float16 half8;
typedef __attribute__((ext_vector_type(4))) float floatx4;

__device__ __forceinline__ void load16_to_lds(const void* gptr, void* lptr) {
    __builtin_amdgcn_global_load_lds(
        (const __attribute__((address_space(1))) void*)gptr,
        (__attribute__((address_space(3))) void*)lptr,
        16, 0, 0);
}

// float -> fp16 bits (RTNE). fp16 (10 mantissa bits) vs bf16 (7) cuts every
// quantization stage's error 8x; all intermediates range-safe for fp16.
__device__ __forceinline__ unsigned short f2h_bits(float f) {
    _Float16 h = (_Float16)f;
    union { _Float16 h; unsigned short u; } cvt;
    cvt.h = h;
    return cvt.u;
}

// ---------------------------------------------------------------------------
// KPREP: merged preprocessing (one launch, 92 blocks x 256):
//   bid 0..15  : k0a — wo [1024 cd][128 p] f32 -> woT2 [128 p][1024] fp16,
//                slice-major woT2[p][s*256 + d*8 + (c&7)], s = c>>3.
//   bid 16..79 : k0b — WbT[64 c][256 k] fp16 + bias[64].
//   bid 80..91 : k2a — bitpack mask: pack[i*8+tw] = bits of mask[tw*32..+31][i]
// ---------------------------------------------------------------------------
__global__ __launch_bounds__(256) void kprep(
    const float* __restrict__ wo, unsigned short* __restrict__ woT2,
    const float* __restrict__ wl, const float* __restrict__ bl,
    const float* __restrict__ wr, const float* __restrict__ br,
    unsigned short* __restrict__ WbT, float* __restrict__ bias,
    const int* __restrict__ mask, unsigned int* __restrict__ pack)
{
    __shared__ float ts[64*129];
    const int bid = blockIdx.x;
    const int t   = threadIdx.x;

    if (bid < 16) {
        // ---- k0a: woT2 packing ----
        const int s  = bid >> 2;
        const int dg = bid & 3;
        #pragma unroll
        for (int g = 0; g < 32; g++) {
            int idx = g*256 + t;
            int row = idx >> 7, p = idx & 127;   // row = ci*8 + di
            int ci = row >> 3, di = row & 7;
            int cd = (s*8 + ci)*32 + dg*8 + di;
            ts[row*129 + p] = wo[(size_t)cd*DP + p];
        }
        __syncthreads();
        int p = t >> 1, half = t & 1;
        #pragma unroll
        for (int dq = 0; dq < 4; dq++) {
            int di = half*4 + dq;
            #pragma unroll
            for (int cq = 0; cq < 2; cq++) {
                ushort4 u;
                u.x = f2h_bits(ts[((cq*4+0)*8 + di)*129 + p]);
                u.y = f2h_bits(ts[((cq*4+1)*8 + di)*129 + p]);
                u.z = f2h_bits(ts[((cq*4+2)*8 + di)*129 + p]);
                u.w = f2h_bits(ts[((cq*4+3)*8 + di)*129 + p]);
                *(ushort4*)&woT2[(size_t)p*1024 + s*256 + dg*64 + di*8 + cq*4] = u;
            }
        }
    } else if (bid < 80) {
        // ---- k0b: WbT + bias ----
        const int c = bid - 16, k = t;
        float v = (c < DH) ? wl[k*DH + c] : wr[k*DH + (c - DH)];
        WbT[c*256 + k] = f2h_bits(v);
        if (c == 0 && k < 64) bias[k] = (k < DH) ? bl[k] : br[k - DH];
    } else {
        // ---- k2a: mask bitpack, coalesced over i ----
        int id = (bid - 80)*256 + t;          // 0..3071
        int i = id % NN, tw = id / NN;        // tw in [0,8)
        unsigned int wbits = 0;
        #pragma unroll
        for (int b = 0; b < 32; b++)
            wbits |= (mask[(tw*32 + b)*NN + i] != 0 ? 1u : 0u) << b;
        pack[i*8 + tw] = wbits;
    }
}

// ---------------------------------------------------------------------------
// K2: cinv[i,j] = 1/(popcount-AND over m + EPS)
// ---------------------------------------------------------------------------
__global__ __launch_bounds__(256) void k2_count(
    const unsigned int* __restrict__ pack, float* __restrict__ cinv)
{
    int id = blockIdx.x * 256 + threadIdx.x;
    int i = id / NN, j = id % NN;
    int s = 0;
    #pragma unroll
    for (int tw = 0; tw < 8; tw++)
        s += __popc(pack[i*8 + tw] & pack[j*8 + tw]);
    cinv[id] = 1.0f / ((float)s + EPS);
}

// ---------------------------------------------------------------------------
// K1: LN (f32) + MFMA projection -> Lb/Rb in [ic][m] layout (fp16).
// Frozen from r10 (passing; <61.6 us per the r10 split diagnostic).
// ---------------------------------------------------------------------------
__global__ __launch_bounds__(256, 2) void k1_lnproj(
    const float* __restrict__ x, const int* __restrict__ mask,
    const float* __restrict__ ln_g, const float* __restrict__ ln_b,
    const unsigned short* __restrict__ WbTg, const float* __restrict__ bias,
    unsigned short* __restrict__ Lb, unsigned short* __restrict__ Rb)
{
    __shared__ unsigned short xns[64*264];   // [mlocal][k] padded (+8)
    __shared__ float mfs[64];

    const int i  = blockIdx.x;
    const int mc = blockIdx.y;               // m-chunk (64 rows)
    const int t = threadIdx.x;
    const int l = t & 63, w = t >> 6;
    const int lc = l & 15, quad = l >> 4;
    const int sub = l >> 4, lc4 = l & 15;    // 16-lane group id / lane-in-group

    // gamma/beta for k = g*64 + lc4*4 .. +3
    float4 gk[4], bk[4];
    #pragma unroll
    for (int g = 0; g < 4; g++) {
        gk[g] = *(const float4*)&ln_g[g*64 + lc4*4];
        bk[g] = *(const float4*)&ln_b[g*64 + lc4*4];
    }

    // batch-issue all 16 loads (4 rows x 4 segments per wave)
    float4 v[4][4];
    #pragma unroll
    for (int rr = 0; rr < 4; rr++) {
        int mlocal = w*16 + rr*4 + sub;
        int m = mc*64 + mlocal;
        const float4* xr = (const float4*)&x[((size_t)m*NN + i)*DM];
        #pragma unroll
        for (int g = 0; g < 4; g++)
            v[rr][g] = xr[g*16 + lc4];       // 256B contiguous per instr
    }

    #pragma unroll
    for (int rr = 0; rr < 4; rr++) {
        int mlocal = w*16 + rr*4 + sub;
        int m = mc*64 + mlocal;
        float s = 0.f, s2 = 0.f;
        #pragma unroll
        for (int g = 0; g < 4; g++) {
            float4 vg = v[rr][g];
            s  += vg.x + vg.y + vg.z + vg.w;
            s2 += vg.x*vg.x + vg.y*vg.y + vg.z*vg.z + vg.w*vg.w;
        }
        #pragma unroll
        for (int off = 1; off < 16; off <<= 1) {
            s  += __shfl_xor(s,  off, 64);
            s2 += __shfl_xor(s2, off, 64);
        }
        float mu   = s * (1.0f/DM);
        float var  = s2 * (1.0f/DM) - mu*mu;
        float rstd = rsqrtf(var + EPS);
        #pragma unroll
        for (int g = 0; g < 4; g++) {
            float4 vg = v[rr][g];
            ushort4 u;
            u.x = f2h_bits((vg.x - mu)*rstd*gk[g].x + bk[g].x);
            u.y = f2h_bits((vg.y - mu)*rstd*gk[g].y + bk[g].y);
            u.z = f2h_bits((vg.z - mu)*rstd*gk[g].z + bk[g].z);
            u.w = f2h_bits((vg.w - mu)*rstd*gk[g].w + bk[g].w);
            *(ushort4*)&xns[mlocal*264 + g*64 + lc4*4] = u;
        }
        if (lc4 == 0) mfs[mlocal] = (mask[(size_t)m*NN + i] != 0) ? 1.0f : 0.0f;
    }
    __syncthreads();

    // MFMA: D[m][c] = sum_k xn[m][k] * WbT[c][k]   (fp16 MFMA)
    floatx4 acc[4];
    #pragma unroll
    for (int nt = 0; nt < 4; nt++) acc[nt] = (floatx4){0.f,0.f,0.f,0.f};
    #pragma unroll
    for (int ks = 0; ks < 8; ks++) {
        half8 af = *(const half8*)&xns[(w*16 + lc)*264 + ks*32 + quad*8];
        #pragma unroll
        for (int nt = 0; nt < 4; nt++) {
            half8 bf = *(const half8*)&WbTg[(nt*16 + lc)*256 + ks*32 + quad*8];
            acc[nt] = __builtin_amdgcn_mfma_f32_16x16x32_f16(af, bf, acc[nt], 0, 0, 0);
        }
    }
    __syncthreads();   // done reading xns; reuse as transpose buffer

    // bias + mask, write transposed tile tr[c][mlocal]
    unsigned short* tr = xns;   // [64][72]
    #pragma unroll
    for (int nt = 0; nt < 4; nt++) {
        int c = nt*16 + lc;
        float bv = bias[c];
        #pragma unroll
        for (int rg = 0; rg < 4; rg++) {
            int mlocal = w*16 + quad*4 + rg;
            tr[c*72 + mlocal] = f2h_bits((acc[nt][rg] + bv) * mfs[mlocal]);
        }
    }
    __syncthreads();

    // write out: thread t -> c = t>>2, m-segment (t&3)*16 (contig in m)
    {
        int c = t >> 2, seg = t & 3;
        unsigned short* dst = (c < DH)
            ? &Lb[((size_t)(i*DH + c))*MM + mc*64 + seg*16]
            : &Rb[((size_t)(i*DH + (c - DH)))*MM + mc*64 + seg*16];
        #pragma unroll
        for (int q = 0; q < 4; q++)
            *(ushort4*)&dst[q*4] = *(ushort4*)&tr[c*72 + seg*16 + q*4];
    }
}

// ---------------------------------------------------------------------------
// K3f: fused GEMM1 + projection, 256x256 tile, 8 waves (512 thr), fp16.
// Single 2304-block dispatch (the r10 4-way split cost ~14 us of L2 reuse;
// its diagnostic purpose is complete).
// K-loop v2: TRIPLE-buffered (96 KB LDS), ONE barrier per K-step.
//   Safety invariant: STAGE at step t (issued after barrier t +
//   sched_barrier) writes buf[(t+2)%3] == buf[(t-1)%3], whose readers
//   (step t-1's ds_reads) completed before their consuming MFMAs issued
//   (compiler lgkmcnt on true data deps), which in turn precede barrier t
//   in program order for every wave. vmcnt(4)/(0) schedule unchanged
//   (FIFO accounting verified for all steps incl. tail).
// Occupancy is register-pinned (128 acc VGPRs -> 2 waves/SIMD), so the
// 96 KB LDS does not change blocks/CU (1 either way).
// Epilogue unchanged: __syncthreads() then 4 K-slice rounds over
// gp[64 pairs][264], fused GEMM2, cinv from the precomputed table.
// ---------------------------------------------------------------------------
__global__ __launch_bounds__(512, 2) void k3f_gemm(
    const unsigned short* __restrict__ Lb,   // [NIC][MM] fp16
    const unsigned short* __restrict__ Rb,   // [NIC][MM] fp16
    const unsigned short* __restrict__ woT2, // [128 p][1024] slice-major fp16
    const float* __restrict__ bo, const float* __restrict__ cinv,
    float* __restrict__ out)
{
    __shared__ short smem[49152];            // 96 KB: 3 x (A 16K | B 16K); union gp[64][264]
    const int t = threadIdx.x;
    const int l = t & 63, w = t >> 6;
    const int wx = w & 3, wy = w >> 2;
    const int lc = l & 15, quad = l >> 4;

    // XCD-aware bijective swizzle, A-panel-resident walk (2304 = 8*48*6)
    int bid = blockIdx.x;
    int xcd = bid & 7;
    int local = bid >> 3;        // 0..287
    int bx = local / 6;          // 0..47, slow-varying within XCD
    int by = xcd * 6 + (local % 6);

    const size_t arow0 = (size_t)bx * 256;
    const size_t brow0 = (size_t)by * 256;

    // staging decode: thread t owns 16B chunks pos0 = t, pos1 = 512+t
    const int pos0 = t, pos1 = 512 + t;
    const int line0 = pos0 >> 3, c0 = (pos0 & 7) ^ (line0 & 7);
    const int r0 = line0*2 + (c0 >> 2), k00 = (c0 & 3) * 8;
    const int line1 = pos1 >> 3, c1 = (pos1 & 7) ^ (line1 & 7);
    const int r1 = line1*2 + (c1 >> 2), k01 = (c1 & 3) * 8;

    const unsigned short* srcA0 = Lb + (arow0 + r0)*MM + k00;
    const unsigned short* srcA1 = Lb + (arow0 + r1)*MM + k01;
    const unsigned short* srcB0 = Rb + (brow0 + r0)*MM + k00;
    const unsigned short* srcB1 = Rb + (brow0 + r1)*MM + k01;

    floatx4 acc[8][4];
    #pragma unroll
    for (int a = 0; a < 8; a++)
        #pragma unroll
        for (int b = 0; b < 4; b++) acc[a][b] = (floatx4){0.f,0.f,0.f,0.f};

#define STAGE(bsel, step) do {                                           \
        char* sb = (char*)smem + (bsel)*32768;                           \
        load16_to_lds(srcA0 + (step)*32, sb + pos0*16);                  \
        load16_to_lds(srcA1 + (step)*32, sb + pos1*16);                  \
        load16_to_lds(srcB0 + (step)*32, sb + 16384 + pos0*16);          \
        load16_to_lds(srcB1 + (step)*32, sb + 16384 + pos1*16);          \
    } while (0)

    STAGE(0, 0);
    STAGE(1, 1);
    #pragma unroll
    for (int tstep = 0; tstep < 8; tstep++) {
        if (tstep < 7) asm volatile("s_waitcnt vmcnt(4)" ::: "memory");
        else           asm volatile("s_waitcnt vmcnt(0)" ::: "memory");
        __builtin_amdgcn_s_barrier();
        __builtin_amdgcn_sched_barrier(0);   // pin: nothing crosses the barrier
        // prefetch 2 tiles ahead into the freed buffer (see invariant above)
        if (tstep + 2 < 8) STAGE((tstep + 2) % 3, tstep + 2);
        const char* Ab = (const char*)smem + (tstep % 3)*32768;
        const char* Bb = Ab + 16384;
        half8 bfr[4];
        #pragma unroll
        for (int nt = 0; nt < 4; nt++) {
            int r = wx*64 + nt*16 + lc;
            int li = r >> 1, cc = ((r & 1)*4 + quad) ^ (li & 7);
            bfr[nt] = *(const half8*)(Bb + li*128 + cc*16);
        }
        __builtin_amdgcn_s_setprio(1);
        #pragma unroll
        for (int mt = 0; mt < 8; mt++) {
            int r = wy*128 + mt*16 + lc;
            int li = r >> 1, cc = ((r & 1)*4 + quad) ^ (li & 7);
            half8 af = *(const half8*)(Ab + li*128 + cc*16);
            #pragma unroll
            for (int nt = 0; nt < 4; nt++)
                acc[mt][nt] = __builtin_amdgcn_mfma_f32_16x16x32_f16(
                    af, bfr[nt], acc[mt][nt], 0, 0, 0);
        }
        __builtin_amdgcn_s_setprio(0);
        // no second barrier: next iteration's barrier provides the fence
    }
#undef STAGE

    __syncthreads();   // all waves done with K-loop LDS before gp reuse

    // --- epilogue: 4 K-slice rounds, gp union in smem ---
    short* gp = smem;                        // [64 pairs][264]
    const int prow = w*16 + lc;              // p column owned by this lane
    floatx4 acc2[4];
    #pragma unroll
    for (int a = 0; a < 4; a++) acc2[a] = (floatx4){0.f,0.f,0.f,0.f};

    #pragma unroll
    for (int s = 0; s < 4; s++) {
        // prefetch this round's woT2 rows (latency hidden under the scatter)
        half8 b2r[8];
        #pragma unroll
        for (int ks = 0; ks < 8; ks++)
            b2r[ks] = *(const half8*)&woT2[(size_t)prow*1024 + s*256 + ks*32 + quad*8];

        // scatter slice s: elements with c>>3 == s.  c = (mt&1)*16+quad*4+rg
        // -> needs quad>>1 == (s&1) and mt&1 == (s>>1).  kk = d*8 + (c&7).
        if ((quad >> 1) == (s & 1)) {
            #pragma unroll
            for (int mmi = 0; mmi < 4; mmi++) {
                const int mt = (s >> 1) + mmi*2;
                #pragma unroll
                for (int nt = 0; nt < 4; nt++) {
                    int pair = (wy*4 + (mt >> 1))*8 + (wx*2 + (nt >> 1));
                    int d = (nt & 1)*16 + lc;
                    int kk = d*8 + (quad & 1)*4;
                    ushort4 u;
                    u.x = f2h_bits(acc[mt][nt][0]);
                    u.y = f2h_bits(acc[mt][nt][1]);
                    u.z = f2h_bits(acc[mt][nt][2]);
                    u.w = f2h_bits(acc[mt][nt][3]);
                    *(ushort4*)&gp[pair*264 + kk] = u;
                }
            }
        }
        __syncthreads();

        // GEMM2 partial: all 64 pairs x 16 p (this wave) x K-slice 256
        __builtin_amdgcn_s_setprio(1);
        #pragma unroll
        for (int ks = 0; ks < 8; ks++) {
            #pragma unroll
            for (int mt2 = 0; mt2 < 4; mt2++) {
                half8 a2 = *(const half8*)&gp[(mt2*16 + lc)*264 + ks*32 + quad*8];
                acc2[mt2] = __builtin_amdgcn_mfma_f32_16x16x32_f16(
                    a2, b2r[ks], acc2[mt2], 0, 0, 0);
            }
        }
        __builtin_amdgcn_s_setprio(0);
        __syncthreads();
    }

    const float bv = bo[prow];
    #pragma unroll
    for (int mt2 = 0; mt2 < 4; mt2++) {
        #pragma unroll
        for (int rg = 0; rg < 4; rg++) {
            int pair = mt2*16 + quad*4 + rg;
            int i = bx*8 + (pair >> 3);
            int j = by*8 + (pair & 7);
            out[((size_t)(i*NN + j))*DP + prow] =
                (acc2[mt2][rg] + bv) * cinv[i*NN + j];
        }
    }
}

// ---------------------------------------------------------------------------
extern "C" void kernel_launch(void* const* d_in, const int* in_sizes, int n_in,
                              void* d_out, int out_size, void* d_ws, size_t ws_size,
                              hipStream_t stream)
{
    const float* x    = (const float*)d_in[0];
    const int*   mask = (const int*)d_in[1];
    const float* ln_g = (const float*)d_in[2];
    const float* ln_b = (const float*)d_in[3];
    const float* wl   = (const float*)d_in[4];
    const float* bl   = (const float*)d_in[5];
    const float* wr   = (const float*)d_in[6];
    const float* br   = (const float*)d_in[7];
    const float* wo   = (const float*)d_in[8];
    const float* bo   = (const float*)d_in[9];
    float* out = (float*)d_out;

    char* ws = (char*)d_ws;
    size_t off = 0;
    unsigned short* Lb   = (unsigned short*)(ws + off); off += (size_t)NIC*MM*2;  // 6.29 MB
    unsigned short* Rb   = (unsigned short*)(ws + off); off += (size_t)NIC*MM*2;  // 6.29 MB
    unsigned short* woT2 = (unsigned short*)(ws + off); off += (size_t)DP*1024*2; // 0.26 MB
    unsigned short* WbTg = (unsigned short*)(ws + off); off += (size_t)64*256*2;  // 32 KB
    float*          bias = (float*)(ws + off);          off += 64*4;
    float*          cinv = (float*)(ws + off);          off += (size_t)NN*NN*4;   // 0.59 MB
    // pack aliases Lb (12 KB, transient): written by kprep, read by k2_count,
    // both complete (stream order) before k1 writes Lb. Keeps the workspace
    // footprint at the proven 13.46 MB maximum.
    unsigned int*   pack = (unsigned int*)Lb;

    kprep<<<92, 256, 0, stream>>>(wo, woT2, wl, bl, wr, br, WbTg, bias, mask, pack);
    k2_count<<<(NN*NN)/256, 256, 0, stream>>>(pack, cinv);
    k1_lnproj<<<dim3(NN, MM/64), 256, 0, stream>>>(x, mask, ln_g, ln_b, WbTg, bias, Lb, Rb);
    k3f_gemm<<<2304, 512, 0, stream>>>(Lb, Rb, woT2, bo, cinv, out);
}